// Round 1
// 1965.661 us; speedup vs baseline: 1.1143x; 1.1143x over previous
//
#include <hip/hip_runtime.h>
#include <hip/hip_bf16.h>
#include <math.h>

typedef __bf16 bf16x8 __attribute__((ext_vector_type(8)));
typedef float floatx4 __attribute__((ext_vector_type(4)));

#define T_LEN 128

// ws layout: bf16 fragment-packed weights (unchanged)
#define WP_OFF   0
#define WP_SZ    (64*10*64*16)     // gates: 64 ct x 10 ki x 64 lanes x 16B = 655360
#define W1P_OFF  (WP_OFF + WP_SZ)
#define W1P_SZ   (8*8*64*16)       // 65536
#define W2P_OFF  (W1P_OFF + W1P_SZ)
#define W2P_SZ   (8*4*64*16)       // 32768
#define WZP_OFF  (W2P_OFF + W2P_SZ)
#define WZP_SZ   (4*4*64*16)       // 16384
#define WS_NEEDED ((size_t)(WZP_OFF + WZP_SZ))   // 770048 B

// ---- fast transcendentals: v_exp_f32 / v_log_f32 / v_rcp_f32 based ------
#if __has_builtin(__builtin_amdgcn_exp2f)
#define EXP2F(x) __builtin_amdgcn_exp2f(x)
#else
#define EXP2F(x) exp2f(x)
#endif
#if __has_builtin(__builtin_amdgcn_logf)
#define LOG2F(x) __builtin_amdgcn_logf(x)
#else
#define LOG2F(x) log2f(x)
#endif
#if __has_builtin(__builtin_amdgcn_rcpf)
#define RCPF(x) __builtin_amdgcn_rcpf(x)
#else
#define RCPF(x) (1.0f/(x))
#endif

// sigmoid: x->-inf: exp2->+inf, rcp->0 OK; x->+inf: exp2->0, rcp(1)=1 OK
__device__ __forceinline__ float fsigmoid(float x) {
    return RCPF(1.0f + EXP2F(-1.4426950408889634f * x));
}
// tanh = 1 - 2*rcp(1+exp2(2x*log2e)); saturates to +/-1 gracefully at both ends
__device__ __forceinline__ float ftanh(float x) {
    return 1.0f - 2.0f * RCPF(1.0f + EXP2F(2.8853900817779268f * x));
}

// ---------------- prep: f32 weights -> bf16 B-fragment-linear in ws -------
__global__ void prep_kernel(const float* __restrict__ Wih, const float* __restrict__ Whh,
                            const float* __restrict__ W1,  const float* __restrict__ W2,
                            const float* __restrict__ Wz,  unsigned char* __restrict__ ws)
{
    int id = blockIdx.x * blockDim.x + threadIdx.x;
    __bf16* Wp  = (__bf16*)(ws + WP_OFF);
    __bf16* W1p = (__bf16*)(ws + W1P_OFF);
    __bf16* W2p = (__bf16*)(ws + W2P_OFF);
    __bf16* Wzp = (__bf16*)(ws + WZP_OFF);
    if (id < 40960) {                       // gates: 64 ct x 10 ki x 64 lanes
        int rem = id % 640, lane = rem % 64;
        int row = (id / 640) * 16 + (lane & 15);         // gate-output col
        int kb  = (rem / 64) * 32 + (lane >> 4) * 8;
        for (int j = 0; j < 8; ++j) {
            int k = kb + j;
            float v;
            if (k < 40)       v = Wih[row * 40 + k];
            else if (k < 296) v = Whh[row * 256 + (k - 40)];
            else              v = 0.0f;                   // K-pad 296..319
            Wp[(size_t)id * 8 + j] = (__bf16)v;
        }
    } else if (id < 45056) {                // W1: 8 ct x 8 ki
        int id2 = id - 40960;
        int rem = id2 % 512, lane = rem % 64;
        int row = (id2 / 512) * 16 + (lane & 15);
        int kb  = (rem / 64) * 32 + (lane >> 4) * 8;
        for (int j = 0; j < 8; ++j) W1p[(size_t)id2 * 8 + j] = (__bf16)W1[row * 256 + kb + j];
    } else if (id < 47104) {                // W2: 8 ct x 4 ki
        int id3 = id - 45056;
        int rem = id3 % 256, lane = rem % 64;
        int row = (id3 / 256) * 16 + (lane & 15);
        int kb  = (rem / 64) * 32 + (lane >> 4) * 8;
        for (int j = 0; j < 8; ++j) W2p[(size_t)id3 * 8 + j] = (__bf16)W2[row * 128 + kb + j];
    } else if (id < 48128) {                // Wz: 4 ct x 4 ki
        int id4 = id - 47104;
        int rem = id4 % 256, lane = rem % 64;
        int row = (id4 / 256) * 16 + (lane & 15);
        int kb  = (rem / 64) * 32 + (lane >> 4) * 8;
        for (int j = 0; j < 8; ++j) Wzp[(size_t)id4 * 8 + j] = (__bf16)Wz[row * 128 + kb + j];
    }
}

// ---------------- fast path: 64 blocks x 1024 threads, 16 rows/block ------
// R8 restructure:
//  * gate weights: global -> VGPR double-buffer (bwA/bwB), MFMA B straight
//    from registers. No LDS staging => ~1.3 MB/step of LDS port traffic gone.
//  * MLP weights (W1/W2/Wz, 112KB): copied ONCE into LDS, resident for all
//    128 steps => no per-step re-stream, no DMA drains at barriers.
//  * xh double-buffered => cell needs NO barrier after gates (only reads own
//    acc; writes go to the other buffer). 5 barriers/step (was 6).
//  * fast exp2/rcp/log2 transcendentals in cell + softplus.
__global__ __launch_bounds__(1024) void seq_mfma(
    const float* __restrict__ A,   const float* __restrict__ eps,
    const float* __restrict__ z0,  const float* __restrict__ h0,
    const float* __restrict__ c0,
    const float* __restrict__ bih, const float* __restrict__ bhh,
    const float* __restrict__ b1,  const float* __restrict__ b2,
    const float* __restrict__ bz,
    const unsigned char* __restrict__ ws, float* __restrict__ out)
{
    const int tid  = threadIdx.x;
    const int wave = tid >> 6;
    const int lane = tid & 63;
    const int lrow = lane & 15;
    const int quad = lane >> 4;
    const int n0   = blockIdx.x * 16;

    // resident MLP weights: W1 (32768 bf16) | W2 (16384) | Wz (8192)
    __shared__ __align__(16) __bf16 wmlp[(W1P_SZ + W2P_SZ + WZP_SZ) / 2];
    __shared__ __align__(16) __bf16 xh[2][16][328];  // [a(8)|z(32)|h(256)|pad]
    __shared__ __align__(16) __bf16 u1s[16][136];
    __shared__ __align__(16) __bf16 u2s[16][136];
    __shared__ __align__(16) float  zzs[16][68];

    // one-time: MLP weights global -> LDS (7168 x 16B)
    {
        const float4* src = (const float4*)(ws + W1P_OFF);
        float4* dst = (float4*)wmlp;
        for (int i = tid; i < 7168; i += 1024) dst[i] = src[i];
    }
    const __bf16* w1l = wmlp;                  // frag: ct*4096 + ki*512 + lane*8
    const __bf16* w2l = wmlp + 32768;          // frag: ct*2048 + ki*512 + lane*8
    const __bf16* wzl = wmlp + 32768 + 16384;  // frag: ct*2048 + ki*512 + lane*8

    // per-lane global fragment pointers for gate weights (include lane*16)
    const char* gptr[4];
    #pragma unroll
    for (int g = 0; g < 4; ++g)
        gptr[g] = (const char*)ws + WP_OFF + ((size_t)((g * 16 + wave) * 10) * 64 + lane) * 16;

    const int unit = wave * 16 + lrow;
    float gb[4];
    #pragma unroll
    for (int g = 0; g < 4; ++g)
        gb[g] = bih[g * 256 + unit] + bhh[g * 256 + unit];
    float u1b = b1[(wave & 7) * 16 + lrow];
    float u2b = b2[(wave & 7) * 16 + lrow];
    float zzb = bz[(wave & 3) * 16 + lrow];

    float cst[4];
    {
        float cv = c0[unit];
        #pragma unroll
        for (int r = 0; r < 4; ++r) cst[r] = cv;
    }

    // init both xh buffers: z0 | h0 | zero pad (buffer 1 pad must be zeroed
    // since steady-state writes never touch cols 296+)
    for (int idx = tid; idx < 2 * 16 * 320; idx += 1024) {
        int b = idx / (16 * 320);
        int rem = idx % (16 * 320);
        int r = rem / 320, col = 8 + rem % 320;
        float v;
        if (col < 40)       v = z0[col - 8];
        else if (col < 296) v = h0[col - 40];
        else                v = 0.0f;
        xh[b][r][col] = (__bf16)v;
    }
    // stage a(t=0) into buffer 0
    if (tid < 128)
        xh[0][tid >> 3][tid & 7] =
            (__bf16)A[((size_t)(n0 + (tid >> 3)) * T_LEN + 0) * 8 + (tid & 7)];

    for (int t = 0; t < T_LEN; ++t) {
        const int cb = t & 1;        // holds [a_t | z_t | h_t]
        const int nb = cb ^ 1;       // receives [a_{t+1} | z_{t+1} | h_{t+1}]
        __syncthreads();             // B1: xh[cb] fully written (prev z/a/h, init)

        // ---- gate weights: VGPR double-buffer pipeline, B-frags from global
        bf16x8 bwA[4], bwB[4];
        #pragma unroll
        for (int g = 0; g < 4; ++g) bwA[g] = *(const bf16x8*)(gptr[g]);
        #pragma unroll
        for (int g = 0; g < 4; ++g) bwB[g] = *(const bf16x8*)(gptr[g] + 1024);

        floatx4 acc[4];
        #pragma unroll
        for (int g = 0; g < 4; ++g)
            acc[g] = (floatx4){gb[g], gb[g], gb[g], gb[g]};

        #pragma unroll
        for (int ki = 0; ki < 10; ++ki) {
            bf16x8 af = *(const bf16x8*)&xh[cb][lrow][ki * 32 + quad * 8];
            if ((ki & 1) == 0) {
                #pragma unroll
                for (int g = 0; g < 4; ++g)
                    acc[g] = __builtin_amdgcn_mfma_f32_16x16x32_bf16(af, bwA[g], acc[g], 0, 0, 0);
                if (ki + 2 < 10) {
                    #pragma unroll
                    for (int g = 0; g < 4; ++g)
                        bwA[g] = *(const bf16x8*)(gptr[g] + (ki + 2) * 1024);
                }
            } else {
                #pragma unroll
                for (int g = 0; g < 4; ++g)
                    acc[g] = __builtin_amdgcn_mfma_f32_16x16x32_bf16(af, bwB[g], acc[g], 0, 0, 0);
                if (ki + 2 < 10) {
                    #pragma unroll
                    for (int g = 0; g < 4; ++g)
                        bwB[g] = *(const bf16x8*)(gptr[g] + (ki + 2) * 1024);
                }
            }
        }

        // ---- eps/a prefetch issued AFTER the gate loads: they sit newest in
        // the vmcnt queue, so gate-weight waits never stall on them; they are
        // long done by z-phase / next-step a-stage.
        float eps_cur = 0.0f;
        if (tid < 512)
            eps_cur = eps[((size_t)(n0 + (tid >> 5)) * T_LEN + t) * 32 + (tid & 31)];
        float a_nxt = 0.0f;
        if (t + 1 < T_LEN && tid < 128)
            a_nxt = A[((size_t)(n0 + (tid >> 3)) * T_LEN + (t + 1)) * 8 + (tid & 7)];

        // ---- LSTM cell: NO barrier needed (own acc only; writes other buffer)
        #pragma unroll
        for (int r = 0; r < 4; ++r) {
            float iv = fsigmoid(acc[0][r]);
            float fv = fsigmoid(acc[1][r]);
            float gv = ftanh(acc[2][r]);
            float ov = fsigmoid(acc[3][r]);
            float cn = fv * cst[r] + iv * gv;
            cst[r] = cn;
            xh[nb][quad * 4 + r][40 + unit] = (__bf16)(ov * ftanh(cn));
        }
        __syncthreads();   // B2: h_{t+1} staged in xh[nb]

        // ---- u1 = relu(h @ W1^T + b1): waves 0..7, B from resident LDS
        if (wave < 8) {
            const int ct = wave & 7;
            floatx4 a1 = (floatx4){u1b, u1b, u1b, u1b};
            #pragma unroll
            for (int ki = 0; ki < 8; ++ki) {
                bf16x8 af = *(const bf16x8*)&xh[nb][lrow][40 + ki * 32 + quad * 8];
                bf16x8 bf_ = *(const bf16x8*)&w1l[ct * 4096 + ki * 512 + lane * 8];
                a1 = __builtin_amdgcn_mfma_f32_16x16x32_bf16(af, bf_, a1, 0, 0, 0);
            }
            #pragma unroll
            for (int r = 0; r < 4; ++r)
                u1s[quad * 4 + r][wave * 16 + lrow] = (__bf16)fmaxf(a1[r], 0.0f);
        }
        __syncthreads();   // B3: u1s ready

        // ---- u2 = relu(u1 @ W2^T + b2): waves 0..7
        if (wave < 8) {
            const int ct = wave & 7;
            floatx4 a2 = (floatx4){u2b, u2b, u2b, u2b};
            #pragma unroll
            for (int ki = 0; ki < 4; ++ki) {
                bf16x8 af = *(const bf16x8*)&u1s[lrow][ki * 32 + quad * 8];
                bf16x8 bf_ = *(const bf16x8*)&w2l[ct * 2048 + ki * 512 + lane * 8];
                a2 = __builtin_amdgcn_mfma_f32_16x16x32_bf16(af, bf_, a2, 0, 0, 0);
            }
            #pragma unroll
            for (int r = 0; r < 4; ++r)
                u2s[quad * 4 + r][wave * 16 + lrow] = (__bf16)fmaxf(a2[r], 0.0f);
        }
        __syncthreads();   // B4: u2s ready

        // ---- zz = u2 @ Wz^T + bz: waves 0..3
        if (wave < 4) {
            const int ct = wave & 3;
            floatx4 a3 = (floatx4){zzb, zzb, zzb, zzb};
            #pragma unroll
            for (int ki = 0; ki < 4; ++ki) {
                bf16x8 af = *(const bf16x8*)&u2s[lrow][ki * 32 + quad * 8];
                bf16x8 bf_ = *(const bf16x8*)&wzl[ct * 2048 + ki * 512 + lane * 8];
                a3 = __builtin_amdgcn_mfma_f32_16x16x32_bf16(af, bf_, a3, 0, 0, 0);
            }
            #pragma unroll
            for (int r = 0; r < 4; ++r)
                zzs[quad * 4 + r][wave * 16 + lrow] = a3[r];
        }
        __syncthreads();   // B5: zzs ready

        // ---- z = loc + softplus(raw)*eps; write f32 out + bf16 feedback.
        // a-stage for t+1 merged here (same buffer, disjoint cols) — saves
        // the old top-of-loop barrier.
        if (tid < 512) {
            int r = tid >> 5, c = tid & 31;
            float loc = zzs[r][c];
            float raw = zzs[r][c + 32];
            float sp  = (raw > 20.0f)
                      ? raw
                      : 0.6931471805599453f *
                        LOG2F(1.0f + EXP2F(1.4426950408889634f * raw));
            float zv  = loc + sp * eps_cur;
            xh[nb][r][8 + c] = (__bf16)zv;
            out[((size_t)(n0 + r) * T_LEN + t) * 32 + c] = zv;
        }
        if (tid < 128)
            xh[nb][tid >> 3][tid & 7] = (__bf16)a_nxt;   // a_{t+1}
    }
}

// ---------------- fallback: proven R4 VALU kernel (f32 hard-coded) --------
struct SM {
    float zx[4][40]; float h[4][256]; float u1[4][128]; float u2[4][128]; float zz[4][64];
};

__global__ __launch_bounds__(256) void seq_valu(
    const float* __restrict__ A, const float* __restrict__ eps,
    const float* __restrict__ z0, const float* __restrict__ h0, const float* __restrict__ c0,
    const float* __restrict__ Wih, const float* __restrict__ Whh,
    const float* __restrict__ bih, const float* __restrict__ bhh,
    const float* __restrict__ W1, const float* __restrict__ b1,
    const float* __restrict__ W2, const float* __restrict__ b2,
    const float* __restrict__ Wz, const float* __restrict__ bz, float* __restrict__ out)
{
    __shared__ SM sm;
    const int tid = threadIdx.x;
    const int n0  = blockIdx.x * 4;
    if (tid < 128) { int rr = tid >> 5, cc = tid & 31; sm.zx[rr][8 + cc] = z0[cc]; }
    for (int i = tid; i < 4 * 256; i += 256) sm.h[i >> 8][i & 255] = h0[i & 255];
    float c[4];
    #pragma unroll
    for (int rr = 0; rr < 4; ++rr) c[rr] = c0[tid];
    float gbias[4];
    #pragma unroll
    for (int g = 0; g < 4; ++g) gbias[g] = bih[g * 256 + tid] + bhh[g * 256 + tid];

    for (int t = 0; t < T_LEN; ++t) {
        if (tid < 32) { int rr = tid >> 3, cc = tid & 7;
            sm.zx[rr][cc] = A[((size_t)(n0 + rr) * T_LEN + t) * 8 + cc]; }
        __syncthreads();
        float acc[4][4];
        #pragma unroll
        for (int g = 0; g < 4; ++g)
            #pragma unroll
            for (int rr = 0; rr < 4; ++rr) acc[g][rr] = gbias[g];
        for (int k = 0; k < 40; ++k) {
            float xv[4];
            #pragma unroll
            for (int rr = 0; rr < 4; ++rr) xv[rr] = sm.zx[rr][k];
            #pragma unroll
            for (int g = 0; g < 4; ++g) {
                float w = Wih[(size_t)(g * 256 + tid) * 40 + k];
                #pragma unroll
                for (int rr = 0; rr < 4; ++rr) acc[g][rr] += w * xv[rr];
            }
        }
        for (int k = 0; k < 256; ++k) {
            float hv[4];
            #pragma unroll
            for (int rr = 0; rr < 4; ++rr) hv[rr] = sm.h[rr][k];
            #pragma unroll
            for (int g = 0; g < 4; ++g) {
                float w = Whh[(size_t)(g * 256 + tid) * 256 + k];
                #pragma unroll
                for (int rr = 0; rr < 4; ++rr) acc[g][rr] += w * hv[rr];
            }
        }
        __syncthreads();
        #pragma unroll
        for (int rr = 0; rr < 4; ++rr) {
            float iv = 1.0f / (1.0f + expf(-acc[0][rr]));
            float fv = 1.0f / (1.0f + expf(-acc[1][rr]));
            float gv = tanhf(acc[2][rr]);
            float ov = 1.0f / (1.0f + expf(-acc[3][rr]));
            float cn = fv * c[rr] + iv * gv;
            c[rr] = cn;
            sm.h[rr][tid] = ov * tanhf(cn);
        }
        __syncthreads();
        { int col = tid & 127, rb = (tid >> 7) * 2;
          float a0 = b1[col], a1 = a0;
          for (int k = 0; k < 256; ++k) { float w = W1[(size_t)col * 256 + k];
              a0 += w * sm.h[rb][k]; a1 += w * sm.h[rb + 1][k]; }
          sm.u1[rb][col] = fmaxf(a0, 0.0f); sm.u1[rb + 1][col] = fmaxf(a1, 0.0f); }
        __syncthreads();
        { int col = tid & 127, rb = (tid >> 7) * 2;
          float a0 = b2[col], a1 = a0;
          for (int k = 0; k < 128; ++k) { float w = W2[(size_t)col * 128 + k];
              a0 += w * sm.u1[rb][k]; a1 += w * sm.u1[rb + 1][k]; }
          sm.u2[rb][col] = fmaxf(a0, 0.0f); sm.u2[rb + 1][col] = fmaxf(a1, 0.0f); }
        __syncthreads();
        { int rr = tid >> 6, col = tid & 63;
          float a0 = bz[col];
          for (int k = 0; k < 128; ++k) a0 += Wz[(size_t)col * 128 + k] * sm.u2[rr][k];
          sm.zz[rr][col] = a0; }
        __syncthreads();
        if (tid < 128) {
            int rr = tid >> 5, cc = tid & 31;
            float loc = sm.zz[rr][cc], raw = sm.zz[rr][cc + 32];
            float sp  = (raw > 20.0f) ? raw : log1pf(expf(raw));
            float ev  = eps[((size_t)(n0 + rr) * T_LEN + t) * 32 + cc];
            float zv  = loc + sp * ev;
            sm.zx[rr][8 + cc] = zv;
            out[((size_t)(n0 + rr) * T_LEN + t) * 32 + cc] = zv;
        }
        __syncthreads();
    }
}

extern "C" void kernel_launch(void* const* d_in, const int* in_sizes, int n_in,
                              void* d_out, int out_size, void* d_ws, size_t ws_size,
                              hipStream_t stream)
{
    const float* A   = (const float*)d_in[0];
    const float* eps = (const float*)d_in[1];
    const float* z0  = (const float*)d_in[2];
    const float* h0  = (const float*)d_in[3];
    const float* c0  = (const float*)d_in[4];
    const float* Wih = (const float*)d_in[5];
    const float* Whh = (const float*)d_in[6];
    const float* bih = (const float*)d_in[7];
    const float* bhh = (const float*)d_in[8];
    const float* W1  = (const float*)d_in[9];
    const float* b1  = (const float*)d_in[10];
    const float* W2  = (const float*)d_in[11];
    const float* b2  = (const float*)d_in[12];
    const float* Wz  = (const float*)d_in[13];
    const float* bz  = (const float*)d_in[14];
    float* out = (float*)d_out;

    if (ws_size >= WS_NEEDED) {
        prep_kernel<<<188, 256, 0, stream>>>(Wih, Whh, W1, W2, Wz, (unsigned char*)d_ws);
        seq_mfma<<<64, 1024, 0, stream>>>(A, eps, z0, h0, c0,
                                          bih, bhh, b1, b2, bz,
                                          (const unsigned char*)d_ws, out);
    } else {
        seq_valu<<<256, 256, 0, stream>>>(A, eps, z0, h0, c0, Wih, Whh, bih, bhh,
                                          W1, b1, W2, b2, Wz, bz, out);
    }
}